// Round 3
// baseline (586.856 us; speedup 1.0000x reference)
//
#include <hip/hip_runtime.h>

#define DIM_OUT 64
#define ALPHA 0.5f
#define BLOCK 256
#define CHUNK 16            // orders staged per LDS pass -> 4 passes
#define NF4 (CHUNK / 4)     // 4 float4 slots per row per pass

// One thread per row runs the serial Gegenbauer recurrence (fully unrolled,
// all coefficients compile-time). Results are staged per 16-order chunk in a
// [BLOCK][4]-float4 LDS tile with an XOR swizzle on the float4 slot
// (phys = s ^ ((row>>1)&3)). Row stride is 64B so both sides use b128 LDS ops,
// and the swizzle gives exactly 8 touches/bank (the b128 conflict floor) for
// both the compute-phase writes and the flush reads. Flush: 4 consecutive
// lanes write one full 64B line (float4 each) -> every line fully written by
// one instruction, no partial-line write amplification.
// 16 KB LDS + VGPR<=64 (launch_bounds 256,8) -> 8 blocks/CU = 32 waves/CU.
__global__ __launch_bounds__(BLOCK, 8) void geg_kernel(const float* __restrict__ x,
                                                       float* __restrict__ out,
                                                       int n) {
    __shared__ float4 lds[BLOCK * NF4];   // 256*4*16B = 16 KB

    const int tid = threadIdx.x;
    const size_t base_row = (size_t)blockIdx.x * BLOCK;
    const size_t row = base_row + tid;

    const float xv = (row < (size_t)n) ? x[row] : 0.0f;

    float prev2 = 1.0f;               // C_0
    float prev  = 2.0f * ALPHA * xv;  // C_1

    const int wsw = (tid >> 1) & 3;   // write-side swizzle key (constant per thread)

    #pragma unroll
    for (int chunk = 0; chunk < DIM_OUT / CHUNK; ++chunk) {
        // ---- compute CHUNK orders into float4 regs, one b128 LDS write each ----
        #pragma unroll
        for (int s = 0; s < NF4; ++s) {
            float v0, v1, v2, v3;
            #pragma unroll
            for (int k = 0; k < 4; ++k) {
                const int ord = chunk * CHUNK + s * 4 + k + 1;  // order 1..64
                float ci;
                if (ord == 1) {
                    ci = prev;        // C_1 already in 'prev'
                } else {
                    const float a   = (2.0f * (float)ord - 2.0f + 2.0f * ALPHA);
                    const float b   = (-(float)ord + 2.0f - 2.0f * ALPHA);
                    const float inv = 1.0f / (float)ord;
                    ci = (a * xv * prev + b * prev2) * inv;   // same assoc as verified kernel
                    prev2 = prev;
                    prev  = ci;
                }
                if (k == 0) v0 = ci; else if (k == 1) v1 = ci;
                else if (k == 2) v2 = ci; else v3 = ci;
            }
            lds[tid * NF4 + (s ^ wsw)] = make_float4(v0, v1, v2, v3);
        }
        __syncthreads();

        // ---- flush: 256 rows x 4 f4 = 1024 float4, 4 per thread ----
        // lane-minor c4: 4 consecutive lanes cover one full 64B line.
        #pragma unroll
        for (int j = 0; j < 4; ++j) {
            const int f  = j * BLOCK + tid;   // float4 index within the tile
            const int r  = f >> 2;            // row within block
            const int c4 = f & 3;             // f4 column within the chunk
            const size_t grow = base_row + r;
            if (grow < (size_t)n) {
                float4 v = lds[r * NF4 + (c4 ^ ((r >> 1) & 3))];
                *(float4*)(out + grow * DIM_OUT + chunk * CHUNK + c4 * 4) = v;
            }
        }
        __syncthreads();   // reads done before next chunk overwrites
    }
}

extern "C" void kernel_launch(void* const* d_in, const int* in_sizes, int n_in,
                              void* d_out, int out_size, void* d_ws, size_t ws_size,
                              hipStream_t stream) {
    const float* x = (const float*)d_in[0];
    float* out = (float*)d_out;
    int n = in_sizes[0];   // 2,000,000 rows (x is [n,1])

    const int grid = (n + BLOCK - 1) / BLOCK;
    geg_kernel<<<grid, BLOCK, 0, stream>>>(x, out, n);
}

// Round 4
// 503.415 us; speedup vs baseline: 1.1657x; 1.1657x over previous
//
#include <hip/hip_runtime.h>

#define DIM_OUT 64
#define ALPHA 0.5f
#define BLOCK 256
#define NF4 (DIM_OUT / 4)   // 16 float4 per output row

// One thread per row runs the serial Gegenbauer recurrence (fully unrolled,
// all coefficients compile-time). The ENTIRE 256x64 tile is staged in 64 KB
// of LDS so the kernel has exactly ONE barrier, placed before any global
// store is issued: the compiler's vmcnt(0)-before-s_barrier drain (which
// serialized round-2/3's multi-phase variants) never gates a store phase.
//
// LDS layout: [256 rows][16 float4], row stride 256B, with XOR swizzle
// phys = s ^ (row&7). Write side: fixed s across 64 lanes -> phys low-3 bits
// cycle through all 8 4-bank groups -> 8 touches/bank (b128 conflict floor).
// Read side: wave = 4 rows x 16 cols, phys = c4 ^ (r&7) covers each bank
// group 8x -> floor. Both sides pure ds_*_b128: 32 LDS instr/thread total
// (vs 128 b32 in the round-2 pad layout).
//
// Flush: 16 consecutive lanes cover one full 256B row -> perfectly coalesced,
// every 64B line fully written by a single instruction. Stores are issued and
// the wave retires; nothing in-kernel waits on them.
// 64 KB LDS -> 2 blocks/CU; ~30 blocks/CU of grid turnover hides phase gaps.
__global__ __launch_bounds__(BLOCK) void geg_kernel(const float* __restrict__ x,
                                                    float* __restrict__ out,
                                                    int n) {
    __shared__ float4 lds[BLOCK * NF4];   // 256*16*16B = 64 KB

    const int tid = threadIdx.x;
    const size_t base_row = (size_t)blockIdx.x * BLOCK;
    const size_t row = base_row + tid;

    const float xv = (row < (size_t)n) ? x[row] : 0.0f;

    float prev2 = 1.0f;               // C_0
    float prev  = 2.0f * ALPHA * xv;  // C_1

    const int wsw = tid & 7;          // write-side swizzle key

    // ---- compute all 64 orders, 4 at a time, one b128 LDS write each ----
    #pragma unroll
    for (int s = 0; s < NF4; ++s) {
        float v0, v1, v2, v3;
        #pragma unroll
        for (int k = 0; k < 4; ++k) {
            const int ord = s * 4 + k + 1;     // order 1..64
            float ci;
            if (ord == 1) {
                ci = prev;                     // C_1 already computed
            } else {
                const float a   = (2.0f * (float)ord - 2.0f + 2.0f * ALPHA);
                const float b   = (-(float)ord + 2.0f - 2.0f * ALPHA);
                const float inv = 1.0f / (float)ord;
                ci = (a * xv * prev + b * prev2) * inv;  // same assoc as verified kernels
                prev2 = prev;
                prev  = ci;
            }
            if (k == 0) v0 = ci; else if (k == 1) v1 = ci;
            else if (k == 2) v2 = ci; else v3 = ci;
        }
        lds[tid * NF4 + (s ^ wsw)] = make_float4(v0, v1, v2, v3);
    }

    __syncthreads();   // the ONLY barrier: no global stores issued yet

    // ---- flush: 256 rows x 16 f4 = 4096 float4, 16 per thread ----
    #pragma unroll
    for (int j = 0; j < NF4; ++j) {
        const int f  = j * BLOCK + tid;   // float4 index within the tile
        const int r  = f >> 4;            // row within block (16 f4 per row)
        const int c4 = f & 15;            // f4 column
        const size_t grow = base_row + r;
        if (grow < (size_t)n) {
            float4 v = lds[r * NF4 + (c4 ^ (r & 7))];
            *(float4*)(out + grow * DIM_OUT + c4 * 4) = v;
        }
    }
}

extern "C" void kernel_launch(void* const* d_in, const int* in_sizes, int n_in,
                              void* d_out, int out_size, void* d_ws, size_t ws_size,
                              hipStream_t stream) {
    const float* x = (const float*)d_in[0];
    float* out = (float*)d_out;
    int n = in_sizes[0];   // 2,000,000 rows (x is [n,1])

    const int grid = (n + BLOCK - 1) / BLOCK;
    geg_kernel<<<grid, BLOCK, 0, stream>>>(x, out, n);
}